// Round 9
// baseline (285.049 us; speedup 1.0000x reference)
//
#include <hip/hip_runtime.h>

typedef __attribute__((ext_vector_type(4))) float f32x4;
typedef __attribute__((ext_vector_type(8))) short s16x8;
typedef __attribute__((ext_vector_type(4))) unsigned int u32x4;

#define HW 112
#define PW8 116                   // padded cols in xq8 (2 left, 2 right)
#define ROWS8 (PW8*8)             // shorts per (plane,row) = 928
#define PLANE8 (112*ROWS8)        // shorts per (n,oct) plane = 103,936
#define CHW (64*112*112)          // 802816
#define NG 713615
#define X_F4 6422528

// ws byte offsets
#define XQ8_BYTES 53215232        // 32*8*PLANE8*2
#define WT_OFF    53219328        // XQ8 + 4KB slack (staging over-reads past plane end)
#define SC_OFF    53293056        // WT + 73,728
#define ZP_OFF    59001984        // SC + 5,708,920 (16B aligned); 1KB zeros

__device__ __forceinline__ unsigned short f32_to_bf16_exact(float q) {
    return (unsigned short)(__float_as_uint(q) >> 16);
}
__device__ __forceinline__ unsigned int pack_bf16x2(float a, float b) {
    return __builtin_amdgcn_perm(__float_as_uint(b), __float_as_uint(a), 0x07060302u);
}
__device__ __forceinline__ void scale_from_max(float m, float& scale, float& inv) {
    if (m > 0.f) {
        int e = (int)((__float_as_uint(m) >> 23) & 0xFF) - 127;
        scale = __builtin_ldexpf(1.0f, e - 7);
        inv   = __builtin_ldexpf(1.0f, 7 - e);
    } else { scale = 0.f; inv = 0.f; }
}

// ---- Q1: per-group (36) scales -> sc[g]=(s,inv). Block 2788: weights + zero page. ----
__global__ __launch_bounds__(256) void q1_scales(const float* __restrict__ x,
                                                 const float* __restrict__ w,
                                                 float2* __restrict__ sc,
                                                 unsigned short* __restrict__ wt,
                                                 u32x4* __restrict__ zp) {
    __shared__ float lmax[2304];
    const int b = blockIdx.x, tid = threadIdx.x;

    if (b == 2788) {                              // weights: 1024 groups of 36; zero page
        if (tid < 64) zp[tid] = (u32x4){0u, 0u, 0u, 0u};
        #pragma unroll 1
        for (int rep = 0; rep < 4; ++rep) {
            int g = rep * 256 + tid;
            const float4* p = (const float4*)w + g * 9;
            float vv[36]; float m = 0.f;
            #pragma unroll
            for (int i = 0; i < 9; ++i) {
                float4 v = p[i];
                vv[i*4+0]=v.x; vv[i*4+1]=v.y; vv[i*4+2]=v.z; vv[i*4+3]=v.w;
                m = fmaxf(m, fmaxf(fmaxf(fabsf(v.x), fabsf(v.y)), fmaxf(fabsf(v.z), fabsf(v.w))));
            }
            float s, inv; scale_from_max(m, s, inv);
            #pragma unroll
            for (int j = 0; j < 36; ++j) {
                int flat = g * 36 + j;
                int k = flat / 576, rem = flat % 576;
                int c = rem / 9, pp = rem % 9;
                float q = rintf(vv[j] * inv) * s;
                wt[pp * 4096 + k * 64 + c] = f32_to_bf16_exact(q);
            }
        }
        return;
    }

    long base4 = (long)b * 2304;                  // 256 groups = 2304 float4, contiguous
    #pragma unroll
    for (int it = 0; it < 9; ++it) {
        int i = it * 256 + tid;
        long g4 = base4 + i;
        float m = 0.f;
        if (g4 < X_F4) {
            float4 v = ((const float4*)x)[g4];
            m = fmaxf(fmaxf(fabsf(v.x), fabsf(v.y)), fmaxf(fabsf(v.z), fabsf(v.w)));
        }
        lmax[i] = m;
    }
    __syncthreads();
    int g = b * 256 + tid;
    if (g < NG) {
        float m = 0.f; int o = tid * 9;
        #pragma unroll
        for (int j = 0; j < 9; ++j) m = fmaxf(m, lmax[o + j]);
        float s, inv; scale_from_max(m, s, inv);
        sc[g] = make_float2(s, inv);
    }
}

// ---- Q2: quantize x -> xq8 NHWC8 [n*8+oct][h][116w][8c], pad cols zeroed.
// 4-pixel-quad per thread: 8 x float4 coalesced reads (L3-hot x), 64B contiguous
// write per thread. Group straddle (f%36 > 32) handled by per-element select.
// 3136 blocks; 49 waves per (n,oct) plane -> waves never straddle planes. ----
__global__ __launch_bounds__(256) void q2_quant(const float* __restrict__ x,
                                                const float2* __restrict__ sc,
                                                unsigned short* __restrict__ xq8) {
    int gt = blockIdx.x * 256 + threadIdx.x;      // 802,816 threads
    int plane = gt / 3136;                        // (n*8 + oct), 0..255
    int pq = gt - plane * 3136;
    int p = pq * 4;                               // pixel quad start, 0..12540
    int h = p / 112, ww = p - h * 112;            // ww % 4 == 0
    unsigned short* row = xq8 + (plane * 112 + h) * ROWS8;

    float vals[8][4];
    #pragma unroll
    for (int j = 0; j < 8; ++j) {
        int f = (plane * 8 + j) * 12544 + p;
        float4 xv = *(const float4*)(x + f);
        unsigned g = (unsigned)f / 36u;
        unsigned r = (unsigned)f - g * 36u;
        float2 sA = sc[g];
        float2 sB = (r > 32u) ? sc[g + 1] : sA;   // only load 2nd group when quad straddles
        float fs0 = xv.x, fs1 = xv.y, fs2 = xv.z, fs3 = xv.w;
        float2 s0 = sA;
        float2 s1 = (r + 1 < 36u) ? sA : sB;
        float2 s2 = (r + 2 < 36u) ? sA : sB;
        float2 s3 = (r + 3 < 36u) ? sA : sB;
        vals[j][0] = rintf(fs0 * s0.y) * s0.x;
        vals[j][1] = rintf(fs1 * s1.y) * s1.x;
        vals[j][2] = rintf(fs2 * s2.y) * s2.x;
        vals[j][3] = rintf(fs3 * s3.y) * s3.x;
    }
    #pragma unroll
    for (int k = 0; k < 4; ++k) {
        u32x4 o;
        o.x = pack_bf16x2(vals[0][k], vals[1][k]);
        o.y = pack_bf16x2(vals[2][k], vals[3][k]);
        o.z = pack_bf16x2(vals[4][k], vals[5][k]);
        o.w = pack_bf16x2(vals[6][k], vals[7][k]);
        *(u32x4*)(row + (ww + 2 + k) * 8) = o;    // 4 x 16B = 64B contiguous per thread
    }
    u32x4 z4 = {0u, 0u, 0u, 0u};
    if (ww == 0)        { *(u32x4*)(row) = z4;            *(u32x4*)(row + 8) = z4; }
    else if (ww == 108) { *(u32x4*)(row + 114 * 8) = z4;  *(u32x4*)(row + 115 * 8) = z4; }
}

// ---- conv: persistent, grid 256 (1 block/CU), 7 tiles/block, LDS double-buffer.
// Staging = 52x global_load_lds_dwordx4 (no VGPR hold, no perms): LDS chunk g =
// (oct, r, pix) linear, per-lane SOURCE pre-swizzled pix^oct (bank-conflict fix,
// m173 pattern). OOB rows + pad chunks read the zero page. Single barrier/tile:
// issue(i+1) after barrier(i) -> vmcnt(0) at iter i+1 is nearly free (a full
// compute phase separates issue from wait). 1 block/CU => allocator has the
// whole register file; no launch-bounds pressure (r2/r3/r5/r7 spill lesson). ----
__global__ __launch_bounds__(256) void conv_mfma(const unsigned short* __restrict__ xq8,
                                                 const unsigned short* __restrict__ wt,
                                                 const float* __restrict__ bias,
                                                 float* __restrict__ out,
                                                 const unsigned short* __restrict__ zp) {
    __shared__ unsigned short xs[2][3328 * 8];    // 2 x 53,248 B
    const int tid = threadIdx.x;
    const int wave = tid >> 6, lane = tid & 63;
    const int wl = lane & 15, quad = lane >> 4;
    const int kg = wave & 1, mg = wave >> 1;
    const int bs = blockIdx.x;

    // per-slot tile-independent decode: slot k covers chunk g=(wave*13+k)*64+lane
    unsigned pk13[13];
    #pragma unroll
    for (int k = 0; k < 13; ++k) {
        int g = (wave * 13 + k) * 64 + lane;
        if (g < 3200) {
            int oct = g / 400, rem = g - oct * 400;
            int r = rem / 40, pix = rem - r * 40;
            int pixs = pix ^ oct;                 // source-side swizzle (low 3 bits)
            pk13[k] = ((unsigned)r << 24) | (unsigned)(oct * PLANE8 + pixs * 8);
        } else pk13[k] = 0xFF000000u;             // pad chunk -> zero page
    }

    float bv[2];
    #pragma unroll
    for (int j = 0; j < 2; ++j) bv[j] = bias[kg * 32 + j * 16 + wl];
    int pixb[7];
    #pragma unroll
    for (int mti = 0; mti < 7; ++mti) {
        int m = (mg * 7 + mti) * 16 + wl;
        pixb[mti] = (m / 28) * 40 + (m % 28) + 1; // row*40 + base col j (LP=2 => +1)
    }

    auto issue = [&](int ti, int bi) {
        int t = bs + 256 * ti;
        int st = ((t & 7) * 224) + (t >> 3);      // XCD-chunked swizzle
        int n = st / 56, rem = st - n * 56;
        int h0 = (rem >> 2) * 8, w0 = (rem & 3) * 28;
        const unsigned short* base = xq8 + n * 8 * PLANE8 + w0 * 8;
        #pragma unroll
        for (int k = 0; k < 13; ++k) {
            unsigned pk = pk13[k];
            int r = (int)(pk >> 24);
            int hh = h0 - 1 + r;
            bool ok = (r <= 9) && (hh >= 0) && (hh < HW);
            const unsigned short* src = ok ? (base + (pk & 0xFFFFFFu) + hh * ROWS8) : zp;
            unsigned short* dst = (unsigned short*)&xs[bi][(wave * 13 + k) * 512];
            __builtin_amdgcn_global_load_lds(
                (const __attribute__((address_space(1))) void*)src,
                (__attribute__((address_space(3))) void*)dst, 16, 0, 0);
        }
    };

    issue(0, 0);                                  // prologue: stage tile 0

    #pragma unroll 1
    for (int i = 0; i < 7; ++i) {
        asm volatile("s_waitcnt vmcnt(0)" ::: "memory");  // my gloads for buf[i&1] done
        __builtin_amdgcn_s_barrier();             // all waves' gloads done; prev readers done
        if (i < 6) issue(i + 1, (i + 1) & 1);     // prefetch next tile (hides under compute)

        int t = bs + 256 * i;
        int st = ((t & 7) * 224) + (t >> 3);
        int n = st / 56, rem = st - n * 56;
        int h0 = (rem >> 2) * 8, w0 = (rem & 3) * 28;
        const unsigned short* xb = &xs[i & 1][0];

        f32x4 acc[7][2];
        f32x4 zero = {0.f, 0.f, 0.f, 0.f};
        #pragma unroll
        for (int mti = 0; mti < 7; ++mti) { acc[mti][0] = zero; acc[mti][1] = zero; }

        #pragma unroll
        for (int p = 0; p < 9; ++p) {
            const int dpix = (p / 3) * 40 + (p % 3);
            #pragma unroll
            for (int cs = 0; cs < 2; ++cs) {
                const int oq = cs * 4 + quad;
                s16x8 B0 = *(const s16x8*)(wt + p * 4096 + ((kg * 2 + 0) * 16 + wl) * 64 + cs * 32 + quad * 8);
                s16x8 B1 = *(const s16x8*)(wt + p * 4096 + ((kg * 2 + 1) * 16 + wl) * 64 + cs * 32 + quad * 8);
                s16x8 A[7];
                #pragma unroll
                for (int mti = 0; mti < 7; ++mti) {
                    int pix = pixb[mti] + dpix;
                    A[mti] = *(const s16x8*)(xb + (oq * 400 + (pix ^ oq)) * 8);
                }
                #pragma unroll
                for (int mti = 0; mti < 7; ++mti) {
                    acc[mti][0] = __builtin_amdgcn_mfma_f32_16x16x32_bf16(A[mti], B0, acc[mti][0], 0, 0, 0);
                    acc[mti][1] = __builtin_amdgcn_mfma_f32_16x16x32_bf16(A[mti], B1, acc[mti][1], 0, 0, 0);
                }
            }
        }

        int obase = n * CHW + h0 * HW + w0;
        #pragma unroll
        for (int mti = 0; mti < 7; ++mti) {
            int m0 = (mg * 7 + mti) * 16 + quad * 4;
            int eofs = (m0 / 28) * HW + (m0 % 28);
            #pragma unroll
            for (int j = 0; j < 2; ++j) {
                f32x4 v = acc[mti][j];
                v.x += bv[j]; v.y += bv[j]; v.z += bv[j]; v.w += bv[j];
                *(f32x4*)(out + obase + (kg * 32 + j * 16 + wl) * 12544 + eofs) = v;
            }
        }
    }
}

extern "C" void kernel_launch(void* const* d_in, const int* in_sizes, int n_in,
                              void* d_out, int out_size, void* d_ws, size_t ws_size,
                              hipStream_t stream) {
    const float* x    = (const float*)d_in[0];
    const float* w    = (const float*)d_in[1];
    const float* bias = (const float*)d_in[2];
    float* out = (float*)d_out;
    char* ws = (char*)d_ws;
    unsigned short* xq8 = (unsigned short*)ws;
    unsigned short* wt  = (unsigned short*)(ws + WT_OFF);
    float2*         sc  = (float2*)(ws + SC_OFF);
    unsigned short* zp  = (unsigned short*)(ws + ZP_OFF);

    hipLaunchKernelGGL(q1_scales, dim3(2789), dim3(256), 0, stream, x, w, sc, wt, (u32x4*)zp);
    hipLaunchKernelGGL(q2_quant,  dim3(3136), dim3(256), 0, stream, x, sc, xq8);
    hipLaunchKernelGGL(conv_mfma, dim3(256),  dim3(256), 0, stream, xq8, wt, bias, out, zp);
}

// Round 10
// 253.087 us; speedup vs baseline: 1.1263x; 1.1263x over previous
//
#include <hip/hip_runtime.h>

typedef __attribute__((ext_vector_type(4))) float f32x4;
typedef __attribute__((ext_vector_type(8))) short s16x8;
typedef __attribute__((ext_vector_type(4))) unsigned int u32x4;

#define HW 112
#define ROWS8 (116*8)             // shorts per (plane,row) = 928 (116 slots x 8c)
#define PLANE8 (112*ROWS8)        // shorts per (n,oct) plane = 103,936
#define CHW (64*112*112)          // 802816
#define X_ELEMS 25690112

// ws byte offsets (kept from r8/r9; conv over-reads <=112B past xq8 -> 4KB slack)
#define WT_OFF    53219328
#define ZP_OFF    59001984

__device__ __forceinline__ unsigned short f32_to_bf16_exact(float q) {
    return (unsigned short)(__float_as_uint(q) >> 16);
}
__device__ __forceinline__ unsigned int pack_bf16x2(float a, float b) {
    return __builtin_amdgcn_perm(__float_as_uint(b), __float_as_uint(a), 0x07060302u);
}
__device__ __forceinline__ void scale_from_max(float m, float& scale, float& inv) {
    if (m > 0.f) {
        int e = (int)((__float_as_uint(m) >> 23) & 0xFF) - 127;
        scale = __builtin_ldexpf(1.0f, e - 7);
        inv   = __builtin_ldexpf(1.0f, 7 - e);
    } else { scale = 0.f; inv = 0.f; }
}

// ---- QW: weights -> wt [pos=9][k=64][c=64] bf16; block 0 also zero page. ----
__global__ __launch_bounds__(256) void qw_kernel(const float* __restrict__ w,
                                                 unsigned short* __restrict__ wt,
                                                 u32x4* __restrict__ zp) {
    if (blockIdx.x == 0 && threadIdx.x < 64) zp[threadIdx.x] = (u32x4){0u, 0u, 0u, 0u};
    int g = blockIdx.x * 256 + threadIdx.x;       // 1024 groups of 36
    const float4* p = (const float4*)w + g * 9;
    float vv[36]; float m = 0.f;
    #pragma unroll
    for (int i = 0; i < 9; ++i) {
        float4 v = p[i];
        vv[i*4+0]=v.x; vv[i*4+1]=v.y; vv[i*4+2]=v.z; vv[i*4+3]=v.w;
        m = fmaxf(m, fmaxf(fmaxf(fabsf(v.x), fabsf(v.y)), fmaxf(fabsf(v.z), fabsf(v.w))));
    }
    float s, inv; scale_from_max(m, s, inv);
    #pragma unroll
    for (int j = 0; j < 36; ++j) {
        int flat = g * 36 + j;
        int k = flat / 576, rem = flat % 576;
        int c = rem / 9, pp = rem % 9;
        float q = rintf(vv[j] * inv) * s;
        wt[pp * 4096 + k * 64 + c] = f32_to_bf16_exact(q);
    }
}

// ---- QX: ONE pass over x. Block = (n,oct) plane x 4 rows (448 px) x 8 channels.
// Group boundaries are float4-aligned (36g and plane offsets are mult of 4), so
// each group = 9 grain-maxes; +-8 grain halo covers straddling groups (both
// neighbor blocks recompute them from identical global data -> identical scales).
// Phase A: load grains (coalesced float4), grain-max -> lmax, values -> LDS.
// Phase B: 120 group scales from lmax.  Phase C: quantize, 8-ch pack, 16B
// coalesced stores to xq8 NHWC8 [plane][h][116w][8c] incl. zeroed pad cols.
// LDS 19.5KB -> 8 blocks/CU (32 waves/CU). Grid 256 planes x 28 chunks. ----
__global__ __launch_bounds__(256) void qx_fused(const float* __restrict__ x,
                                                unsigned short* __restrict__ xq8) {
    __shared__ float vals[8 * 448];               // f32 values, this chunk, 8 channels
    __shared__ float lmax[1024];                  // 8 ch x 128 grains (112 + 2x8 halo)
    __shared__ float2 ssc[8][16];                 // per-channel group (s, inv)
    __shared__ int sgs[8];                        // per-channel first group id
    const int tid = threadIdx.x;
    const int b = blockIdx.x;
    const int plane = b / 28, chunk = b - plane * 28;
    const int p0 = chunk * 448;
    const int base_plane = plane * 8 * 12544;     // flat base of channel oct*8 of image n

    #pragma unroll
    for (int it = 0; it < 4; ++it) {
        int g = it * 256 + tid;
        int j = g >> 7, gi = g & 127;
        int flat = base_plane + j * 12544 + p0 - 32 + gi * 4;
        float4 v = {0.f, 0.f, 0.f, 0.f};
        if (flat >= 0 && flat < X_ELEMS) v = *(const float4*)(x + flat);  // 16B aligned
        lmax[g] = fmaxf(fmaxf(fabsf(v.x), fabsf(v.y)), fmaxf(fabsf(v.z), fabsf(v.w)));
        if (gi >= 8 && gi < 120)
            *(f32x4*)&vals[j * 448 + (gi - 8) * 4] = (f32x4){v.x, v.y, v.z, v.w};
    }
    __syncthreads();

    if (tid < 128) {
        int j = tid >> 4, k = tid & 15;
        unsigned a0 = (unsigned)(base_plane + j * 12544 + p0);
        int gstart = (int)(a0 / 36u);
        int gend   = (int)((a0 + 447u) / 36u);
        if (k == 0) sgs[j] = gstart;
        if (gstart + k <= gend) {
            int ps = 36 * (gstart + k) - (int)a0;  // group start rel. p0, in [-32, 444], 4-aligned
            int gb = ps / 4 + 8;                   // first grain index in lmax[j][.]
            float m = 0.f;
            #pragma unroll
            for (int q = 0; q < 9; ++q) m = fmaxf(m, lmax[j * 128 + gb + q]);
            float s, inv; scale_from_max(m, s, inv);
            ssc[j][k] = make_float2(s, inv);
        }
    }
    __syncthreads();

    const int hrow0 = chunk * 4;
    #pragma unroll
    for (int it = 0; it < 2; ++it) {
        int s = it * 256 + tid;
        if (s < 464) {                            // 4 rows x 116 slots (incl. pads)
            int h = s / 116, w = s - h * 116;
            unsigned short* dst = xq8 + (plane * 112 + hrow0 + h) * ROWS8 + w * 8;
            u32x4 o = {0u, 0u, 0u, 0u};
            if (w >= 2 && w < 114) {
                int dp = h * 112 + (w - 2);
                unsigned pbase = (unsigned)(base_plane + p0 + dp);
                float qv[8];
                #pragma unroll
                for (int j = 0; j < 8; ++j) {
                    float v = vals[j * 448 + dp];
                    unsigned g = (pbase + (unsigned)j * 12544u) / 36u;
                    float2 sv = ssc[j][(int)g - sgs[j]];
                    qv[j] = rintf(v * sv.y) * sv.x;
                }
                o.x = pack_bf16x2(qv[0], qv[1]);
                o.y = pack_bf16x2(qv[2], qv[3]);
                o.z = pack_bf16x2(qv[4], qv[5]);
                o.w = pack_bf16x2(qv[6], qv[7]);
            }
            *(u32x4*)dst = o;                     // coalesced 16B/lane
        }
    }
}

// ---- conv: UNCHANGED from r8/r9 (verified twice). Persistent, grid 256,
// 7 tiles/block, LDS double-buffer, 52x global_load_lds_dwordx4 staging with
// source-side pix^oct swizzle; zero page for OOB rows. ----
__global__ __launch_bounds__(256) void conv_mfma(const unsigned short* __restrict__ xq8,
                                                 const unsigned short* __restrict__ wt,
                                                 const float* __restrict__ bias,
                                                 float* __restrict__ out,
                                                 const unsigned short* __restrict__ zp) {
    __shared__ unsigned short xs[2][3328 * 8];    // 2 x 53,248 B
    const int tid = threadIdx.x;
    const int wave = tid >> 6, lane = tid & 63;
    const int wl = lane & 15, quad = lane >> 4;
    const int kg = wave & 1, mg = wave >> 1;
    const int bs = blockIdx.x;

    unsigned pk13[13];
    #pragma unroll
    for (int k = 0; k < 13; ++k) {
        int g = (wave * 13 + k) * 64 + lane;
        if (g < 3200) {
            int oct = g / 400, rem = g - oct * 400;
            int r = rem / 40, pix = rem - r * 40;
            int pixs = pix ^ oct;
            pk13[k] = ((unsigned)r << 24) | (unsigned)(oct * PLANE8 + pixs * 8);
        } else pk13[k] = 0xFF000000u;
    }

    float bv[2];
    #pragma unroll
    for (int j = 0; j < 2; ++j) bv[j] = bias[kg * 32 + j * 16 + wl];
    int pixb[7];
    #pragma unroll
    for (int mti = 0; mti < 7; ++mti) {
        int m = (mg * 7 + mti) * 16 + wl;
        pixb[mti] = (m / 28) * 40 + (m % 28) + 1;
    }

    auto issue = [&](int ti, int bi) {
        int t = bs + 256 * ti;
        int st = ((t & 7) * 224) + (t >> 3);
        int n = st / 56, rem = st - n * 56;
        int h0 = (rem >> 2) * 8, w0 = (rem & 3) * 28;
        const unsigned short* base = xq8 + n * 8 * PLANE8 + w0 * 8;
        #pragma unroll
        for (int k = 0; k < 13; ++k) {
            unsigned pk = pk13[k];
            int r = (int)(pk >> 24);
            int hh = h0 - 1 + r;
            bool ok = (r <= 9) && (hh >= 0) && (hh < HW);
            const unsigned short* src = ok ? (base + (pk & 0xFFFFFFu) + hh * ROWS8) : zp;
            unsigned short* dst = (unsigned short*)&xs[bi][(wave * 13 + k) * 512];
            __builtin_amdgcn_global_load_lds(
                (const __attribute__((address_space(1))) void*)src,
                (__attribute__((address_space(3))) void*)dst, 16, 0, 0);
        }
    };

    issue(0, 0);

    #pragma unroll 1
    for (int i = 0; i < 7; ++i) {
        asm volatile("s_waitcnt vmcnt(0)" ::: "memory");
        __builtin_amdgcn_s_barrier();
        if (i < 6) issue(i + 1, (i + 1) & 1);

        int t = bs + 256 * i;
        int st = ((t & 7) * 224) + (t >> 3);
        int n = st / 56, rem = st - n * 56;
        int h0 = (rem >> 2) * 8, w0 = (rem & 3) * 28;
        const unsigned short* xb = &xs[i & 1][0];

        f32x4 acc[7][2];
        f32x4 zero = {0.f, 0.f, 0.f, 0.f};
        #pragma unroll
        for (int mti = 0; mti < 7; ++mti) { acc[mti][0] = zero; acc[mti][1] = zero; }

        #pragma unroll
        for (int p = 0; p < 9; ++p) {
            const int dpix = (p / 3) * 40 + (p % 3);
            #pragma unroll
            for (int cs = 0; cs < 2; ++cs) {
                const int oq = cs * 4 + quad;
                s16x8 B0 = *(const s16x8*)(wt + p * 4096 + ((kg * 2 + 0) * 16 + wl) * 64 + cs * 32 + quad * 8);
                s16x8 B1 = *(const s16x8*)(wt + p * 4096 + ((kg * 2 + 1) * 16 + wl) * 64 + cs * 32 + quad * 8);
                s16x8 A[7];
                #pragma unroll
                for (int mti = 0; mti < 7; ++mti) {
                    int pix = pixb[mti] + dpix;
                    A[mti] = *(const s16x8*)(xb + (oq * 400 + (pix ^ oq)) * 8);
                }
                #pragma unroll
                for (int mti = 0; mti < 7; ++mti) {
                    acc[mti][0] = __builtin_amdgcn_mfma_f32_16x16x32_bf16(A[mti], B0, acc[mti][0], 0, 0, 0);
                    acc[mti][1] = __builtin_amdgcn_mfma_f32_16x16x32_bf16(A[mti], B1, acc[mti][1], 0, 0, 0);
                }
            }
        }

        int obase = n * CHW + h0 * HW + w0;
        #pragma unroll
        for (int mti = 0; mti < 7; ++mti) {
            int m0 = (mg * 7 + mti) * 16 + quad * 4;
            int eofs = (m0 / 28) * HW + (m0 % 28);
            #pragma unroll
            for (int j = 0; j < 2; ++j) {
                f32x4 v = acc[mti][j];
                v.x += bv[j]; v.y += bv[j]; v.z += bv[j]; v.w += bv[j];
                *(f32x4*)(out + obase + (kg * 32 + j * 16 + wl) * 12544 + eofs) = v;
            }
        }
    }
}

extern "C" void kernel_launch(void* const* d_in, const int* in_sizes, int n_in,
                              void* d_out, int out_size, void* d_ws, size_t ws_size,
                              hipStream_t stream) {
    const float* x    = (const float*)d_in[0];
    const float* w    = (const float*)d_in[1];
    const float* bias = (const float*)d_in[2];
    float* out = (float*)d_out;
    char* ws = (char*)d_ws;
    unsigned short* xq8 = (unsigned short*)ws;
    unsigned short* wt  = (unsigned short*)(ws + WT_OFF);
    unsigned short* zp  = (unsigned short*)(ws + ZP_OFF);

    hipLaunchKernelGGL(qw_kernel, dim3(4),    dim3(256), 0, stream, w, wt, (u32x4*)zp);
    hipLaunchKernelGGL(qx_fused,  dim3(7168), dim3(256), 0, stream, x, xq8);
    hipLaunchKernelGGL(conv_mfma, dim3(256),  dim3(256), 0, stream, xq8, wt, bias, out, zp);
}

// Round 11
// 250.093 us; speedup vs baseline: 1.1398x; 1.0120x over previous
//
#include <hip/hip_runtime.h>

typedef __attribute__((ext_vector_type(4))) float f32x4;
typedef __attribute__((ext_vector_type(8))) short s16x8;
typedef __attribute__((ext_vector_type(4))) unsigned int u32x4;

#define HW 112
#define ROWS8 (116*8)             // shorts per (plane,row) = 928 (116 slots x 8c)
#define PLANE8 (112*ROWS8)        // shorts per (n,oct) plane = 103,936
#define CHW (64*112*112)          // 802816
#define X_ELEMS 25690112

// ws byte offsets (kept from r8-r10; conv over-reads <=112B past xq8 -> 4KB slack)
#define WT_OFF    53219328
#define ZP_OFF    59001984

__device__ __forceinline__ unsigned short f32_to_bf16_exact(float q) {
    return (unsigned short)(__float_as_uint(q) >> 16);
}
__device__ __forceinline__ unsigned int pack_bf16x2(float a, float b) {
    return __builtin_amdgcn_perm(__float_as_uint(b), __float_as_uint(a), 0x07060302u);
}
__device__ __forceinline__ void scale_from_max(float m, float& scale, float& inv) {
    if (m > 0.f) {
        int e = (int)((__float_as_uint(m) >> 23) & 0xFF) - 127;
        scale = __builtin_ldexpf(1.0f, e - 7);
        inv   = __builtin_ldexpf(1.0f, 7 - e);
    } else { scale = 0.f; inv = 0.f; }
}

// ---- QX: ONE pass over x (r10 structure, unchanged x-path). Blocks 7168-7171
// run the weight path instead (saves a launch); block 7168 also zeroes zp. ----
__global__ __launch_bounds__(256) void qx_fused(const float* __restrict__ x,
                                                const float* __restrict__ w,
                                                unsigned short* __restrict__ xq8,
                                                unsigned short* __restrict__ wt,
                                                u32x4* __restrict__ zp) {
    __shared__ float vals[8 * 448];               // f32 values, this chunk, 8 channels
    __shared__ float lmax[1024];                  // 8 ch x 128 grains (112 + 2x8 halo)
    __shared__ float2 ssc[8][16];                 // per-channel group (s, inv)
    __shared__ int sgs[8];                        // per-channel first group id
    const int tid = threadIdx.x;
    const int b = blockIdx.x;

    if (b >= 7168) {                              // ---- weight path: 1024 groups of 36
        if (b == 7168 && tid < 64) zp[tid] = (u32x4){0u, 0u, 0u, 0u};
        int g = (b - 7168) * 256 + tid;
        const float4* p = (const float4*)w + g * 9;
        float vv[36]; float m = 0.f;
        #pragma unroll
        for (int i = 0; i < 9; ++i) {
            float4 v = p[i];
            vv[i*4+0]=v.x; vv[i*4+1]=v.y; vv[i*4+2]=v.z; vv[i*4+3]=v.w;
            m = fmaxf(m, fmaxf(fmaxf(fabsf(v.x), fabsf(v.y)), fmaxf(fabsf(v.z), fabsf(v.w))));
        }
        float s, inv; scale_from_max(m, s, inv);
        #pragma unroll
        for (int j = 0; j < 36; ++j) {
            int flat = g * 36 + j;
            int k = flat / 576, rem = flat % 576;
            int c = rem / 9, pp = rem % 9;
            float q = rintf(vv[j] * inv) * s;
            wt[pp * 4096 + k * 64 + c] = f32_to_bf16_exact(q);
        }
        return;
    }

    const int plane = b / 28, chunk = b - plane * 28;
    const int p0 = chunk * 448;
    const int base_plane = plane * 8 * 12544;     // flat base of channel oct*8 of image n

    #pragma unroll
    for (int it = 0; it < 4; ++it) {
        int g = it * 256 + tid;
        int j = g >> 7, gi = g & 127;
        int flat = base_plane + j * 12544 + p0 - 32 + gi * 4;
        float4 v = {0.f, 0.f, 0.f, 0.f};
        if (flat >= 0 && flat < X_ELEMS) v = *(const float4*)(x + flat);  // 16B aligned
        lmax[g] = fmaxf(fmaxf(fabsf(v.x), fabsf(v.y)), fmaxf(fabsf(v.z), fabsf(v.w)));
        if (gi >= 8 && gi < 120)
            *(f32x4*)&vals[j * 448 + (gi - 8) * 4] = (f32x4){v.x, v.y, v.z, v.w};
    }
    __syncthreads();

    if (tid < 128) {
        int j = tid >> 4, k = tid & 15;
        unsigned a0 = (unsigned)(base_plane + j * 12544 + p0);
        int gstart = (int)(a0 / 36u);
        int gend   = (int)((a0 + 447u) / 36u);
        if (k == 0) sgs[j] = gstart;
        if (gstart + k <= gend) {
            int ps = 36 * (gstart + k) - (int)a0;  // group start rel. p0, in [-32, 444], 4-aligned
            int gb = ps / 4 + 8;                   // first grain index in lmax[j][.]
            float m = 0.f;
            #pragma unroll
            for (int q = 0; q < 9; ++q) m = fmaxf(m, lmax[j * 128 + gb + q]);
            float s, inv; scale_from_max(m, s, inv);
            ssc[j][k] = make_float2(s, inv);
        }
    }
    __syncthreads();

    const int hrow0 = chunk * 4;
    #pragma unroll
    for (int it = 0; it < 2; ++it) {
        int s = it * 256 + tid;
        if (s < 464) {                            // 4 rows x 116 slots (incl. pads)
            int h = s / 116, w2 = s - h * 116;
            unsigned short* dst = xq8 + (plane * 112 + hrow0 + h) * ROWS8 + w2 * 8;
            u32x4 o = {0u, 0u, 0u, 0u};
            if (w2 >= 2 && w2 < 114) {
                int dp = h * 112 + (w2 - 2);
                unsigned pbase = (unsigned)(base_plane + p0 + dp);
                float qv[8];
                #pragma unroll
                for (int j = 0; j < 8; ++j) {
                    float v = vals[j * 448 + dp];
                    unsigned g = (pbase + (unsigned)j * 12544u) / 36u;
                    float2 sv = ssc[j][(int)g - sgs[j]];
                    qv[j] = rintf(v * sv.y) * sv.x;
                }
                o.x = pack_bf16x2(qv[0], qv[1]);
                o.y = pack_bf16x2(qv[2], qv[3]);
                o.z = pack_bf16x2(qv[4], qv[5]);
                o.w = pack_bf16x2(qv[6], qv[7]);
            }
            *(u32x4*)dst = o;                     // coalesced 16B/lane
        }
    }
}

// ---- conv: r8-r10 structure; ONE change: counted vmcnt (T4). Per iteration the
// vector-memory issue order is {13 gload_lds} -> {B-loads, consumed} -> {14 output
// stores}; at the next wait, vmcnt(14) completes everything except the newest 14
// (the stores) -> the gloads are guaranteed landed, and the store-completion
// latency (~300-600cyc, 7x/block) leaves the critical path. Iter 0 keeps
// vmcnt(0) (only 13 gloads outstanding; 14 would not wait at all). ----
__global__ __launch_bounds__(256) void conv_mfma(const unsigned short* __restrict__ xq8,
                                                 const unsigned short* __restrict__ wt,
                                                 const float* __restrict__ bias,
                                                 float* __restrict__ out,
                                                 const unsigned short* __restrict__ zp) {
    __shared__ unsigned short xs[2][3328 * 8];    // 2 x 53,248 B
    const int tid = threadIdx.x;
    const int wave = tid >> 6, lane = tid & 63;
    const int wl = lane & 15, quad = lane >> 4;
    const int kg = wave & 1, mg = wave >> 1;
    const int bs = blockIdx.x;

    unsigned pk13[13];
    #pragma unroll
    for (int k = 0; k < 13; ++k) {
        int g = (wave * 13 + k) * 64 + lane;
        if (g < 3200) {
            int oct = g / 400, rem = g - oct * 400;
            int r = rem / 40, pix = rem - r * 40;
            int pixs = pix ^ oct;
            pk13[k] = ((unsigned)r << 24) | (unsigned)(oct * PLANE8 + pixs * 8);
        } else pk13[k] = 0xFF000000u;
    }

    float bv[2];
    #pragma unroll
    for (int j = 0; j < 2; ++j) bv[j] = bias[kg * 32 + j * 16 + wl];
    int pixb[7];
    #pragma unroll
    for (int mti = 0; mti < 7; ++mti) {
        int m = (mg * 7 + mti) * 16 + wl;
        pixb[mti] = (m / 28) * 40 + (m % 28) + 1;
    }

    auto issue = [&](int ti, int bi) {
        int t = bs + 256 * ti;
        int st = ((t & 7) * 224) + (t >> 3);
        int n = st / 56, rem = st - n * 56;
        int h0 = (rem >> 2) * 8, w0 = (rem & 3) * 28;
        const unsigned short* base = xq8 + n * 8 * PLANE8 + w0 * 8;
        #pragma unroll
        for (int k = 0; k < 13; ++k) {
            unsigned pk = pk13[k];
            int r = (int)(pk >> 24);
            int hh = h0 - 1 + r;
            bool ok = (r <= 9) && (hh >= 0) && (hh < HW);
            const unsigned short* src = ok ? (base + (pk & 0xFFFFFFu) + hh * ROWS8) : zp;
            unsigned short* dst = (unsigned short*)&xs[bi][(wave * 13 + k) * 512];
            __builtin_amdgcn_global_load_lds(
                (const __attribute__((address_space(1))) void*)src,
                (__attribute__((address_space(3))) void*)dst, 16, 0, 0);
        }
    };

    issue(0, 0);

    #pragma unroll 1
    for (int i = 0; i < 7; ++i) {
        if (i == 0) asm volatile("s_waitcnt vmcnt(0)" ::: "memory");
        else        asm volatile("s_waitcnt vmcnt(14)" ::: "memory");  // all but newest 14 (stores)
        __builtin_amdgcn_s_barrier();
        if (i < 6) issue(i + 1, (i + 1) & 1);

        int t = bs + 256 * i;
        int st = ((t & 7) * 224) + (t >> 3);
        int n = st / 56, rem = st - n * 56;
        int h0 = (rem >> 2) * 8, w0 = (rem & 3) * 28;
        const unsigned short* xb = &xs[i & 1][0];

        f32x4 acc[7][2];
        f32x4 zero = {0.f, 0.f, 0.f, 0.f};
        #pragma unroll
        for (int mti = 0; mti < 7; ++mti) { acc[mti][0] = zero; acc[mti][1] = zero; }

        #pragma unroll
        for (int p = 0; p < 9; ++p) {
            const int dpix = (p / 3) * 40 + (p % 3);
            #pragma unroll
            for (int cs = 0; cs < 2; ++cs) {
                const int oq = cs * 4 + quad;
                s16x8 B0 = *(const s16x8*)(wt + p * 4096 + ((kg * 2 + 0) * 16 + wl) * 64 + cs * 32 + quad * 8);
                s16x8 B1 = *(const s16x8*)(wt + p * 4096 + ((kg * 2 + 1) * 16 + wl) * 64 + cs * 32 + quad * 8);
                s16x8 A[7];
                #pragma unroll
                for (int mti = 0; mti < 7; ++mti) {
                    int pix = pixb[mti] + dpix;
                    A[mti] = *(const s16x8*)(xb + (oq * 400 + (pix ^ oq)) * 8);
                }
                #pragma unroll
                for (int mti = 0; mti < 7; ++mti) {
                    acc[mti][0] = __builtin_amdgcn_mfma_f32_16x16x32_bf16(A[mti], B0, acc[mti][0], 0, 0, 0);
                    acc[mti][1] = __builtin_amdgcn_mfma_f32_16x16x32_bf16(A[mti], B1, acc[mti][1], 0, 0, 0);
                }
            }
        }

        int obase = n * CHW + h0 * HW + w0;
        #pragma unroll
        for (int mti = 0; mti < 7; ++mti) {
            int m0 = (mg * 7 + mti) * 16 + quad * 4;
            int eofs = (m0 / 28) * HW + (m0 % 28);
            #pragma unroll
            for (int j = 0; j < 2; ++j) {
                f32x4 v = acc[mti][j];
                v.x += bv[j]; v.y += bv[j]; v.z += bv[j]; v.w += bv[j];
                *(f32x4*)(out + obase + (kg * 32 + j * 16 + wl) * 12544 + eofs) = v;
            }
        }
    }
}

extern "C" void kernel_launch(void* const* d_in, const int* in_sizes, int n_in,
                              void* d_out, int out_size, void* d_ws, size_t ws_size,
                              hipStream_t stream) {
    const float* x    = (const float*)d_in[0];
    const float* w    = (const float*)d_in[1];
    const float* bias = (const float*)d_in[2];
    float* out = (float*)d_out;
    char* ws = (char*)d_ws;
    unsigned short* xq8 = (unsigned short*)ws;
    unsigned short* wt  = (unsigned short*)(ws + WT_OFF);
    unsigned short* zp  = (unsigned short*)(ws + ZP_OFF);

    hipLaunchKernelGGL(qx_fused,  dim3(7172), dim3(256), 0, stream, x, w, xq8, wt, (u32x4*)zp);
    hipLaunchKernelGGL(conv_mfma, dim3(256),  dim3(256), 0, stream, xq8, wt, bias, out, zp);
}